// Round 14
// baseline (62.187 us; speedup 1.0000x reference)
//
#include <hip/hip_runtime.h>
#include <hip/hip_bf16.h>
#include <stdint.h>

#define BB 4
#define SS 4096
#define EE 1024
#define DD 64

typedef __attribute__((ext_vector_type(8))) short short8;
typedef __attribute__((ext_vector_type(4))) float f32x4;

__device__ inline uint32_t cvtpk(float lo, float hi) {
    uint32_t r;
    asm("v_cvt_pk_bf16_f32 %0, %1, %2" : "=v"(r) : "v"(lo), "v"(hi));
    return r;
}
__device__ inline float bf2f_lo(uint32_t u) {
    union { uint32_t u; float f; } v; v.u = u << 16; return v.f;
}
__device__ inline float bf2f_hi(uint32_t u) {
    union { uint32_t u; float f; } v; v.u = u & 0xFFFF0000u; return v.f;
}

#define GL16(g, l) __builtin_amdgcn_global_load_lds( \
    (const __attribute__((address_space(1))) void*)(g), \
    (__attribute__((address_space(3))) void*)(l), 16, 0, 0)

// ---------- W f32 -> bf16 concat [192][1024]: rows 0-63 Wq, 64-127 Wk, 128-191 Wv ----------
__global__ __launch_bounds__(256) void wconv_kernel(
    const float* __restrict__ Wq, const float* __restrict__ Wk,
    const float* __restrict__ Wv, ushort* __restrict__ Wb)
{
    int tid = blockIdx.x * 256 + threadIdx.x;
    int sel = tid >> 13;
    int off = (tid & 8191) * 8;
    const float* src = (sel == 0) ? Wq : ((sel == 1) ? Wk : Wv);
    float4 a = *reinterpret_cast<const float4*>(src + off);
    float4 b = *reinterpret_cast<const float4*>(src + off + 4);
    uint4 o;
    o.x = cvtpk(a.x, a.y); o.y = cvtpk(a.z, a.w);
    o.z = cvtpk(b.x, b.y); o.w = cvtpk(b.z, b.w);
    *reinterpret_cast<uint4*>(Wb + (size_t)sel * 65536 + off) = o;
}

// ---------- Projection: N-split, M64xN64 blocks, grid 768 -> 3 blocks/CU (12 waves/CU) ----------
// Per buffer: x 64x32 f32 (8KB, src-preswizzled) + W 64x32 bf16 (4KB) = 12KB; 3 bufs = 36KB.
// 3 GL16/thread/tile; steady state vmcnt(6) -> 2 tiles always in flight.
__global__ __launch_bounds__(256) void proj_kernel(
    const float* __restrict__ x, const ushort* __restrict__ Wb,
    ushort* __restrict__ q_ws, ushort* __restrict__ k_ws, ushort* __restrict__ vT_ws)
{
    __shared__ __align__(16) char smem[3 * 12288];
    const int t = threadIdx.x;
    const int wid = t >> 6, lane = t & 63, g = lane >> 4, lr = lane & 15;
    const int sel = blockIdx.x >> 8;          // 0=q, 1=k, 2=v
    const int m0 = (blockIdx.x & 255) * 64;
    const int NT = EE / 32;   // 32 K-steps

    f32x4 acc[4];
#pragma unroll
    for (int i = 0; i < 4; ++i) acc[i] = (f32x4)(0.0f);

#define PSTAGE(KT, BUFI) do { \
    char* xb_ = smem + (BUFI) * 12288; \
    char* wb_ = xb_ + 8192; \
    int e0_ = (KT) * 32; \
    _Pragma("unroll") \
    for (int i = 0; i < 2; ++i) { \
        int v = i * 256 + t; int row = v >> 3, c = v & 7; \
        GL16(&x[(size_t)(m0 + row) * EE + e0_ + ((c ^ (row & 7)) << 2)], xb_ + v * 16); \
    } \
    { \
        int v = t; int row = v >> 2, u = v & 3; \
        GL16(&Wb[(size_t)(sel * 64 + row) * EE + e0_ + ((u ^ (row & 3)) << 3)], wb_ + v * 16); \
    } \
} while (0)

    PSTAGE(0, 0); PSTAGE(1, 1); PSTAGE(2, 2);

    for (int kt = 0; kt < NT; ++kt) {
        asm volatile("s_waitcnt vmcnt(6)" ::: "memory");
        __builtin_amdgcn_s_barrier();
        __builtin_amdgcn_sched_barrier(0);

        const char* xb = smem + (kt % 3) * 12288;
        const char* wb = xb + 8192;

        // A = W rows (n), B = this wave's 16 x-rows (m)
        short8 af[4];
#pragma unroll
        for (int ni = 0; ni < 4; ++ni) {
            int row = ni * 16 + lr;
            af[ni] = *reinterpret_cast<const short8*>(wb + row * 64 + ((g ^ (lr & 3)) << 4));
        }
        short8 bfr;
        {
            int row = wid * 16 + lr;
            int u0 = (2 * g) ^ (lr & 7);
            f32x4 lo = *reinterpret_cast<const f32x4*>(xb + row * 128 + u0 * 16);
            f32x4 hi = *reinterpret_cast<const f32x4*>(xb + row * 128 + (u0 ^ 1) * 16);
            union { short8 s; uint32_t u[4]; } p;
            p.u[0] = cvtpk(lo[0], lo[1]); p.u[1] = cvtpk(lo[2], lo[3]);
            p.u[2] = cvtpk(hi[0], hi[1]); p.u[3] = cvtpk(hi[2], hi[3]);
            bfr = p.s;
        }
#pragma unroll
        for (int ni = 0; ni < 4; ++ni)
            acc[ni] = __builtin_amdgcn_mfma_f32_16x16x32_bf16(af[ni], bfr, acc[ni], 0, 0, 0);

        asm volatile("s_waitcnt lgkmcnt(0)" ::: "memory");
        __builtin_amdgcn_sched_barrier(0);
        __builtin_amdgcn_s_barrier();
        __builtin_amdgcn_sched_barrier(0);

        int nx = (kt + 3 < NT) ? kt + 3 : NT - 1;   // clamped dummy keeps vmcnt uniform
        PSTAGE(nx, kt % 3);
    }

    // epilogue: D[n][m]: n = ni*16+4g+jr -> d, m = m0+wid*16+lr -> (b,s)
    const int m = m0 + wid * 16 + lr;
    const int b = m >> 12, s = m & (SS - 1);
#pragma unroll
    for (int ni = 0; ni < 4; ++ni) {
        int d0 = ni * 16 + 4 * g;
        uint2 p;
        p.x = cvtpk(acc[ni][0], acc[ni][1]);
        p.y = cvtpk(acc[ni][2], acc[ni][3]);
        if (sel == 0) {
            *reinterpret_cast<uint2*>(q_ws + ((size_t)b * SS + s) * DD + d0) = p;
        } else if (sel == 1) {
            *reinterpret_cast<uint2*>(k_ws + ((size_t)b * SS + s) * DD + d0) = p;
        } else {
            vT_ws[((size_t)b * DD + d0 + 0) * SS + s] = (ushort)(p.x & 0xFFFF);
            vT_ws[((size_t)b * DD + d0 + 1) * SS + s] = (ushort)(p.x >> 16);
            vT_ws[((size_t)b * DD + d0 + 2) * SS + s] = (ushort)(p.y & 0xFFFF);
            vT_ws[((size_t)b * DD + d0 + 3) * SS + s] = (ushort)(p.y >> 16);
        }
    }
}

// ---------- Flash attention: 8 waves / 128 q-rows, KVT=128, static-max softmax ----------
__global__ __launch_bounds__(512) void attn_kernel(
    const ushort* __restrict__ q_ws, const ushort* __restrict__ k_ws,
    const ushort* __restrict__ vT_ws, uint32_t* __restrict__ pO32,
    float* __restrict__ pml)
{
    __shared__ __align__(16) char kv_lds[2][32768];   // per buf: K 128x64 (16KB) | V^T 64x128 (16KB)
    const int t = threadIdx.x;
    const int wid = t >> 6, lane = t & 63, g = lane >> 4, lr = lane & 15;
    const int bid = blockIdx.x;
    const int f = bid & 3;
    const int b = (bid >> 2) & 3;
    const int qblk = 31 - (bid >> 4);     // 128-row q-blocks, heavy first
    const int qb_w = qblk * 128 + wid * 16;

    const ushort* qp = q_ws + ((size_t)b * SS + qb_w + lr) * DD;
    short8 qf0 = *reinterpret_cast<const short8*>(qp + g * 8);
    short8 qf1 = *reinterpret_cast<const short8*>(qp + 32 + g * 8);

    float l_r = 0.0f;
    f32x4 acc[4];
#pragma unroll
    for (int i = 0; i < 4; ++i) acc[i] = (f32x4)(0.0f);

    const float sc = 0.125f * 1.44269504f;
    const float MB = 5.770780164f;        // static softmax bias: 4 * log2(e)
    const int nt = qblk + 1;              // kv tiles of 128 for this q-block
    const int nfull = ((qb_w - 127) >> 7) + 1;  // fully-unmasked tiles for THIS wave
    const int cs = (nt + 3) >> 2;
    const int t0 = f * cs;
    const int t1 = min(nt, (f + 1) * cs);
    const ushort* kbase = k_ws + (size_t)b * SS * DD;
    const ushort* vbase = vT_ws + (size_t)b * DD * SS;

    // ds_permute routing (loop-invariant)
    const int s0 = g & 1, hi = g >> 1;
    const int idxA = ((lr + 16 * ((s0 << 1) | hi)) << 2);
    const int idxB = idxA ^ 128;

    // stage one 128-kv tile: K 128 rows x 128B + V^T 64 rows x 256B (src-preswizzled)
#define ASTAGE(KT, BUFI) do { \
    char* kb_ = kv_lds[BUFI]; \
    int kv0_ = (KT) * 128; \
    _Pragma("unroll") \
    for (int i = 0; i < 2; ++i) { \
        int v = i * 512 + t; int row = v >> 3, c = v & 7; \
        GL16(kbase + (size_t)(kv0_ + row) * DD + ((c ^ (row & 7)) << 3), kb_ + v * 16); \
    } \
    _Pragma("unroll") \
    for (int i = 0; i < 2; ++i) { \
        int v = i * 512 + t; int row = v >> 4, c = v & 15; \
        GL16(vbase + (size_t)row * SS + kv0_ + ((c ^ ((row & 7) << 1)) << 3), kb_ + 16384 + v * 16); \
    } \
} while (0)

    if (t0 < t1) {
        ASTAGE(t0, 0);
        ASTAGE((t0 + 1 < t1) ? t0 + 1 : t0, 1);

        for (int kt = t0; kt < t1; ++kt) {
            const int cur = (kt - t0) & 1;
            asm volatile("s_waitcnt vmcnt(4)" ::: "memory");
            __builtin_amdgcn_s_barrier();
            __builtin_amdgcn_sched_barrier(0);

            const char* kb = kv_lds[cur];
            const char* vb = kb + 16384;
            const int kv0 = kt * 128;

            // S^T = K Q^T : sfr[nf][jr] = S[kv0+nf*16+4g+jr][qb_w+lr]
            f32x4 sfr[8];
            __builtin_amdgcn_s_setprio(1);
#pragma unroll
            for (int nf = 0; nf < 8; ++nf) {
                int row = nf * 16 + lr;
                short8 b0 = *reinterpret_cast<const short8*>(kb + row * 128 + ((g ^ (row & 7)) << 4));
                short8 b1 = *reinterpret_cast<const short8*>(kb + row * 128 + (((4 + g) ^ (row & 7)) << 4));
                f32x4 s_ = (f32x4)(0.0f);
                s_ = __builtin_amdgcn_mfma_f32_16x16x32_bf16(b0, qf0, s_, 0, 0, 0);
                s_ = __builtin_amdgcn_mfma_f32_16x16x32_bf16(b1, qf1, s_, 0, 0, 0);
                sfr[nf] = s_;
            }
            __builtin_amdgcn_s_setprio(0);

            // causal mask on raw scores
            if (kt >= nfull) {
#pragma unroll
                for (int nf = 0; nf < 8; ++nf)
#pragma unroll
                    for (int jr = 0; jr < 4; ++jr)
                        if (kv0 + nf * 16 + 4 * g + jr > qb_w + lr) sfr[nf][jr] = -1e30f;
            }

            // static-max softmax: p = exp2(S*sc - MB); no per-tile reduce, no rescale
            float ps = 0.0f;
            uint32_t pk[16];
#pragma unroll
            for (int nf = 0; nf < 8; ++nf) {
                float e0_ = exp2f(fmaf(sfr[nf][0], sc, -MB));
                float e1_ = exp2f(fmaf(sfr[nf][1], sc, -MB));
                float e2_ = exp2f(fmaf(sfr[nf][2], sc, -MB));
                float e3_ = exp2f(fmaf(sfr[nf][3], sc, -MB));
                ps += (e0_ + e1_) + (e2_ + e3_);
                pk[nf * 2 + 0] = cvtpk(e0_, e1_);
                pk[nf * 2 + 1] = cvtpk(e2_, e3_);
            }
            l_r += ps;   // lane-local; cross-lane reduce deferred to epilogue

            // In-register P transpose: 16 ds_permute pushes (block-replicated routing)
            uint32_t pw[4][4];
#pragma unroll
            for (int cc = 0; cc < 4; ++cc) {
                uint32_t r0 = (uint32_t)__builtin_amdgcn_ds_permute(idxA, (int)(s0 ? pk[cc * 4 + 2] : pk[cc * 4 + 0]));
                uint32_t r1 = (uint32_t)__builtin_amdgcn_ds_permute(idxA, (int)(s0 ? pk[cc * 4 + 3] : pk[cc * 4 + 1]));
                uint32_t r2 = (uint32_t)__builtin_amdgcn_ds_permute(idxB, (int)(s0 ? pk[cc * 4 + 0] : pk[cc * 4 + 2]));
                uint32_t r3 = (uint32_t)__builtin_amdgcn_ds_permute(idxB, (int)(s0 ? pk[cc * 4 + 1] : pk[cc * 4 + 3]));
                pw[cc][0] = hi ? r2 : r0;
                pw[cc][1] = hi ? r3 : r1;
                pw[cc][2] = hi ? r0 : r2;
                pw[cc][3] = hi ? r1 : r3;
            }

            // O^T += V^T P : A = V^T rows from LDS, B = P fragment (in-register)
            __builtin_amdgcn_s_setprio(1);
#pragma unroll
            for (int cc = 0; cc < 4; ++cc) {
                union { uint32_t u[4]; short8 s; } pb;
                pb.u[0] = pw[cc][0]; pb.u[1] = pw[cc][1];
                pb.u[2] = pw[cc][2]; pb.u[3] = pw[cc][3];
#pragma unroll
                for (int df = 0; df < 4; ++df) {
                    int row = df * 16 + lr;
                    short8 vb_ = *reinterpret_cast<const short8*>(
                        vb + row * 256 + (((cc * 4 + g) ^ ((row & 7) << 1)) << 4));
                    acc[df] = __builtin_amdgcn_mfma_f32_16x16x32_bf16(vb_, pb.s, acc[df], 0, 0, 0);
                }
            }
            __builtin_amdgcn_s_setprio(0);

            // all LDS reads from this buffer done before DMA overwrites it
            asm volatile("s_waitcnt lgkmcnt(0)" ::: "memory");
            __builtin_amdgcn_sched_barrier(0);
            __builtin_amdgcn_s_barrier();
            __builtin_amdgcn_sched_barrier(0);

            int nx = (kt + 2 < t1) ? kt + 2 : t1 - 1;   // clamped dummy keeps vmcnt uniform
            ASTAGE(nx, cur);
        }
    }

    // epilogue: single cross-lane l reduce; store partial O^T (bf16) + l
    l_r += __shfl_xor(l_r, 16);
    l_r += __shfl_xor(l_r, 32);
    const int pidx = ((b * 256 + qblk * 8 + wid) * 4 + f);
    uint32_t* po = pO32 + (size_t)pidx * 512;
#pragma unroll
    for (int df = 0; df < 4; ++df) {
        po[(df * 8 + 2 * g + 0) * 16 + lr] = cvtpk(acc[df][0], acc[df][1]);
        po[(df * 8 + 2 * g + 1) * 16 + lr] = cvtpk(acc[df][2], acc[df][3]);
    }
    if (g == 0) pml[(size_t)pidx * 16 + lr] = l_r;
}

// ---------- Combine partials (weight-free: static softmax bias) ----------
__global__ __launch_bounds__(64) void combine_kernel(
    const uint32_t* __restrict__ pO32, const float* __restrict__ pml,
    float* __restrict__ out)
{
    const int t = threadIdx.x;
    const int q = t & 15, dblk = t >> 4;
    const int grp = blockIdx.x;          // b*256 + qt16
    const int b = grp >> 8, qt = grp & 255;
    const int qb = qt * 16;

    float l = 0.0f;
#pragma unroll
    for (int f = 0; f < 4; ++f) l += pml[(size_t)(grp * 4 + f) * 16 + q];

    float o[16];
#pragma unroll
    for (int i = 0; i < 16; ++i) o[i] = 0.0f;
#pragma unroll
    for (int f = 0; f < 4; ++f) {
        const uint32_t* src = pO32 + (size_t)(grp * 4 + f) * 512 + dblk * 128 + q;
#pragma unroll
        for (int r0 = 0; r0 < 8; ++r0) {
            uint32_t u = src[r0 * 16];
            o[2 * r0 + 0] += bf2f_lo(u);
            o[2 * r0 + 1] += bf2f_hi(u);
        }
    }
    float inv = 1.0f / l;
    float* op = out + ((size_t)b * SS + qb + q) * DD + dblk * 16;
#pragma unroll
    for (int i = 0; i < 4; ++i) {
        float4 st;
        st.x = o[4 * i + 0] * inv; st.y = o[4 * i + 1] * inv;
        st.z = o[4 * i + 2] * inv; st.w = o[4 * i + 3] * inv;
        *reinterpret_cast<float4*>(op + 4 * i) = st;
    }
}

extern "C" void kernel_launch(void* const* d_in, const int* in_sizes, int n_in,
                              void* d_out, int out_size, void* d_ws, size_t ws_size,
                              hipStream_t stream) {
    const float* x  = (const float*)d_in[0];
    const float* Wk = (const float*)d_in[1];
    const float* Wq = (const float*)d_in[2];
    const float* Wv = (const float*)d_in[3];
    ushort* q_ws  = (ushort*)d_ws;
    ushort* k_ws  = q_ws + (size_t)BB * SS * DD;
    ushort* vT_ws = k_ws + (size_t)BB * SS * DD;
    ushort* Wb    = vT_ws + (size_t)BB * SS * DD;
    uint32_t* pO32 = (uint32_t*)(Wb + 192 * 1024);          // 4096 * 512 u32 = 8 MB
    float* pml     = (float*)(pO32 + (size_t)4096 * 512);   // 4096 * 16 f32 = 256 KB
    float* out = (float*)d_out;

    hipLaunchKernelGGL(wconv_kernel, dim3(96), dim3(256), 0, stream, Wq, Wk, Wv, Wb);
    hipLaunchKernelGGL(proj_kernel, dim3(768), dim3(256), 0, stream,
                       x, Wb, q_ws, k_ws, vT_ws);
    hipLaunchKernelGGL(attn_kernel, dim3(BB * 32 * 4), dim3(512), 0, stream,
                       q_ws, k_ws, vT_ws, pO32, pml);
    hipLaunchKernelGGL(combine_kernel, dim3(BB * SS / 16), dim3(64), 0, stream,
                       pO32, pml, out);
}

// Round 15
// 59.584 us; speedup vs baseline: 1.0437x; 1.0437x over previous
//
#include <hip/hip_runtime.h>
#include <hip/hip_bf16.h>
#include <stdint.h>

#define BB 4
#define SS 4096
#define EE 1024
#define DD 64

typedef __attribute__((ext_vector_type(8))) short short8;
typedef __attribute__((ext_vector_type(4))) float f32x4;

__device__ inline uint32_t cvtpk(float lo, float hi) {
    uint32_t r;
    asm("v_cvt_pk_bf16_f32 %0, %1, %2" : "=v"(r) : "v"(lo), "v"(hi));
    return r;
}
__device__ inline float bf2f_lo(uint32_t u) {
    union { uint32_t u; float f; } v; v.u = u << 16; return v.f;
}
__device__ inline float bf2f_hi(uint32_t u) {
    union { uint32_t u; float f; } v; v.u = u & 0xFFFF0000u; return v.f;
}

#define GL16(g, l) __builtin_amdgcn_global_load_lds( \
    (const __attribute__((address_space(1))) void*)(g), \
    (__attribute__((address_space(3))) void*)(l), 16, 0, 0)

// ---------- W f32 -> bf16 concat [192][1024]: rows 0-63 Wq, 64-127 Wk, 128-191 Wv ----------
__global__ __launch_bounds__(256) void wconv_kernel(
    const float* __restrict__ Wq, const float* __restrict__ Wk,
    const float* __restrict__ Wv, ushort* __restrict__ Wb)
{
    int tid = blockIdx.x * 256 + threadIdx.x;
    int sel = tid >> 13;
    int off = (tid & 8191) * 8;
    const float* src = (sel == 0) ? Wq : ((sel == 1) ? Wk : Wv);
    float4 a = *reinterpret_cast<const float4*>(src + off);
    float4 b = *reinterpret_cast<const float4*>(src + off + 4);
    uint4 o;
    o.x = cvtpk(a.x, a.y); o.y = cvtpk(a.z, a.w);
    o.z = cvtpk(b.x, b.y); o.w = cvtpk(b.z, b.w);
    *reinterpret_cast<uint4*>(Wb + (size_t)sel * 65536 + off) = o;
}

// ---------- Projection: K-step 64, 16 iterations, 3 x 40KB buffers (120 KB LDS) ----------
// M=64, N=192 (full), grid 256. Per stage/thread: x 4 GL16 + W 6 GL16 = 10.
// vmcnt(20) = 2 stages always in flight. Final vmcnt(0) drains tail dummies.
__global__ __launch_bounds__(256) void proj_kernel(
    const float* __restrict__ x, const ushort* __restrict__ Wb,
    ushort* __restrict__ q_ws, ushort* __restrict__ k_ws, ushort* __restrict__ vT_ws)
{
    __shared__ __align__(16) char smem[3 * 40960];
    const int t = threadIdx.x;
    const int wid = t >> 6, lane = t & 63, g = lane >> 4, lr = lane & 15;
    const int m0 = blockIdx.x * 64;
    const int NT = EE / 64;   // 16 K-steps

    f32x4 acc[3][4];
#pragma unroll
    for (int ni = 0; ni < 3; ++ni)
#pragma unroll
        for (int mi = 0; mi < 4; ++mi) acc[ni][mi] = (f32x4)(0.0f);

    // x: 64 rows x 256B (16 chunks, slot = c ^ (row&15));  W: 192 rows x 128B (8 chunks, slot = u ^ (row&7))
#define PSTAGE(KT, BUFI) do { \
    char* xb_ = smem + (BUFI) * 40960; \
    char* wb_ = xb_ + 16384; \
    int e0_ = (KT) * 64; \
    _Pragma("unroll") \
    for (int i = 0; i < 4; ++i) { \
        int v = i * 256 + t; int row = v >> 4, c = v & 15; \
        GL16(&x[(size_t)(m0 + row) * EE + e0_ + ((c ^ (row & 15)) << 2)], xb_ + v * 16); \
    } \
    _Pragma("unroll") \
    for (int i = 0; i < 6; ++i) { \
        int v = i * 256 + t; int row = v >> 3, u = v & 7; \
        GL16(&Wb[(size_t)row * EE + e0_ + ((u ^ (row & 7)) << 3)], wb_ + v * 16); \
    } \
} while (0)

    PSTAGE(0, 0); PSTAGE(1, 1); PSTAGE(2, 2);

    for (int kt = 0; kt < NT; ++kt) {
        asm volatile("s_waitcnt vmcnt(20)" ::: "memory");
        __builtin_amdgcn_s_barrier();
        __builtin_amdgcn_sched_barrier(0);

        const char* xb = smem + (kt % 3) * 40960;
        const char* wb = xb + 16384;

        short8 af[3][2], bf[4][2];
#pragma unroll
        for (int ni = 0; ni < 3; ++ni) {
            int row = wid * 48 + ni * 16 + lr;
#pragma unroll
            for (int kc = 0; kc < 2; ++kc)
                af[ni][kc] = *reinterpret_cast<const short8*>(
                    wb + row * 128 + (((kc * 4 + g) ^ (row & 7)) << 4));
        }
#pragma unroll
        for (int mi = 0; mi < 4; ++mi) {
            int row = mi * 16 + lr;
#pragma unroll
            for (int kc = 0; kc < 2; ++kc) {
                int s0_ = (kc * 8 + 2 * g) ^ lr;
                int s1_ = (kc * 8 + 2 * g + 1) ^ lr;
                f32x4 lo = *reinterpret_cast<const f32x4*>(xb + row * 256 + s0_ * 16);
                f32x4 hi = *reinterpret_cast<const f32x4*>(xb + row * 256 + s1_ * 16);
                union { short8 s; uint32_t u[4]; } p;
                p.u[0] = cvtpk(lo[0], lo[1]); p.u[1] = cvtpk(lo[2], lo[3]);
                p.u[2] = cvtpk(hi[0], hi[1]); p.u[3] = cvtpk(hi[2], hi[3]);
                bf[mi][kc] = p.s;
            }
        }
#pragma unroll
        for (int ni = 0; ni < 3; ++ni)
#pragma unroll
            for (int mi = 0; mi < 4; ++mi)
#pragma unroll
                for (int kc = 0; kc < 2; ++kc)
                    acc[ni][mi] = __builtin_amdgcn_mfma_f32_16x16x32_bf16(af[ni][kc], bf[mi][kc], acc[ni][mi], 0, 0, 0);

        asm volatile("s_waitcnt lgkmcnt(0)" ::: "memory");
        __builtin_amdgcn_sched_barrier(0);
        __builtin_amdgcn_s_barrier();
        __builtin_amdgcn_sched_barrier(0);

        int nx = (kt + 3 < NT) ? kt + 3 : NT - 1;   // clamped dummy keeps vmcnt uniform
        PSTAGE(nx, kt % 3);
    }

    // drain tail dummies before epilogue (LDS DMA must not outlive the block)
    asm volatile("s_waitcnt vmcnt(0)" ::: "memory");

    // epilogue: D[n][m]: n = wid*48+ni*16+4g+jr -> (sel,d), m = m0+mi*16+lr -> (b,s)
#pragma unroll
    for (int ni = 0; ni < 3; ++ni) {
        int n0 = wid * 48 + ni * 16 + 4 * g;
        int sel = n0 >> 6, d0 = n0 & 63;
#pragma unroll
        for (int mi = 0; mi < 4; ++mi) {
            int m = m0 + mi * 16 + lr;
            int b = m >> 12, s = m & (SS - 1);
            uint2 p;
            p.x = cvtpk(acc[ni][mi][0], acc[ni][mi][1]);
            p.y = cvtpk(acc[ni][mi][2], acc[ni][mi][3]);
            if (sel == 0) {
                *reinterpret_cast<uint2*>(q_ws + ((size_t)b * SS + s) * DD + d0) = p;
            } else if (sel == 1) {
                *reinterpret_cast<uint2*>(k_ws + ((size_t)b * SS + s) * DD + d0) = p;
            } else {
                vT_ws[((size_t)b * DD + d0 + 0) * SS + s] = (ushort)(p.x & 0xFFFF);
                vT_ws[((size_t)b * DD + d0 + 1) * SS + s] = (ushort)(p.x >> 16);
                vT_ws[((size_t)b * DD + d0 + 2) * SS + s] = (ushort)(p.y & 0xFFFF);
                vT_ws[((size_t)b * DD + d0 + 3) * SS + s] = (ushort)(p.y >> 16);
            }
        }
    }
}

// ---------- Flash attention: 8 waves / 128 q-rows, KVT=128, static-max softmax ----------
__global__ __launch_bounds__(512) void attn_kernel(
    const ushort* __restrict__ q_ws, const ushort* __restrict__ k_ws,
    const ushort* __restrict__ vT_ws, uint32_t* __restrict__ pO32,
    float* __restrict__ pml)
{
    __shared__ __align__(16) char kv_lds[2][32768];   // per buf: K 128x64 (16KB) | V^T 64x128 (16KB)
    const int t = threadIdx.x;
    const int wid = t >> 6, lane = t & 63, g = lane >> 4, lr = lane & 15;
    const int bid = blockIdx.x;
    const int f = bid & 3;
    const int b = (bid >> 2) & 3;
    const int qblk = 31 - (bid >> 4);     // 128-row q-blocks, heavy first
    const int qb_w = qblk * 128 + wid * 16;

    const ushort* qp = q_ws + ((size_t)b * SS + qb_w + lr) * DD;
    short8 qf0 = *reinterpret_cast<const short8*>(qp + g * 8);
    short8 qf1 = *reinterpret_cast<const short8*>(qp + 32 + g * 8);

    float l_r = 0.0f;
    f32x4 acc[4];
#pragma unroll
    for (int i = 0; i < 4; ++i) acc[i] = (f32x4)(0.0f);

    const float sc = 0.125f * 1.44269504f;
    const float MB = 5.770780164f;        // static softmax bias: 4 * log2(e)
    const int nt = qblk + 1;              // kv tiles of 128 for this q-block
    const int nfull = ((qb_w - 127) >> 7) + 1;  // fully-unmasked tiles for THIS wave
    const int cs = (nt + 3) >> 2;
    const int t0 = f * cs;
    const int t1 = min(nt, (f + 1) * cs);
    const ushort* kbase = k_ws + (size_t)b * SS * DD;
    const ushort* vbase = vT_ws + (size_t)b * DD * SS;

    // ds_permute routing (loop-invariant)
    const int s0 = g & 1, hi = g >> 1;
    const int idxA = ((lr + 16 * ((s0 << 1) | hi)) << 2);
    const int idxB = idxA ^ 128;

    // stage one 128-kv tile: K 128 rows x 128B + V^T 64 rows x 256B (src-preswizzled)
#define ASTAGE(KT, BUFI) do { \
    char* kb_ = kv_lds[BUFI]; \
    int kv0_ = (KT) * 128; \
    _Pragma("unroll") \
    for (int i = 0; i < 2; ++i) { \
        int v = i * 512 + t; int row = v >> 3, c = v & 7; \
        GL16(kbase + (size_t)(kv0_ + row) * DD + ((c ^ (row & 7)) << 3), kb_ + v * 16); \
    } \
    _Pragma("unroll") \
    for (int i = 0; i < 2; ++i) { \
        int v = i * 512 + t; int row = v >> 4, c = v & 15; \
        GL16(vbase + (size_t)row * SS + kv0_ + ((c ^ ((row & 7) << 1)) << 3), kb_ + 16384 + v * 16); \
    } \
} while (0)

    if (t0 < t1) {
        ASTAGE(t0, 0);
        ASTAGE((t0 + 1 < t1) ? t0 + 1 : t0, 1);

        for (int kt = t0; kt < t1; ++kt) {
            const int cur = (kt - t0) & 1;
            asm volatile("s_waitcnt vmcnt(4)" ::: "memory");
            __builtin_amdgcn_s_barrier();
            __builtin_amdgcn_sched_barrier(0);

            const char* kb = kv_lds[cur];
            const char* vb = kb + 16384;
            const int kv0 = kt * 128;

            // S^T = K Q^T : sfr[nf][jr] = S[kv0+nf*16+4g+jr][qb_w+lr]
            f32x4 sfr[8];
            __builtin_amdgcn_s_setprio(1);
#pragma unroll
            for (int nf = 0; nf < 8; ++nf) {
                int row = nf * 16 + lr;
                short8 b0 = *reinterpret_cast<const short8*>(kb + row * 128 + ((g ^ (row & 7)) << 4));
                short8 b1 = *reinterpret_cast<const short8*>(kb + row * 128 + (((4 + g) ^ (row & 7)) << 4));
                f32x4 s_ = (f32x4)(0.0f);
                s_ = __builtin_amdgcn_mfma_f32_16x16x32_bf16(b0, qf0, s_, 0, 0, 0);
                s_ = __builtin_amdgcn_mfma_f32_16x16x32_bf16(b1, qf1, s_, 0, 0, 0);
                sfr[nf] = s_;
            }
            __builtin_amdgcn_s_setprio(0);

            // causal mask on raw scores
            if (kt >= nfull) {
#pragma unroll
                for (int nf = 0; nf < 8; ++nf)
#pragma unroll
                    for (int jr = 0; jr < 4; ++jr)
                        if (kv0 + nf * 16 + 4 * g + jr > qb_w + lr) sfr[nf][jr] = -1e30f;
            }

            // static-max softmax: p = exp2(S*sc - MB); no per-tile reduce, no rescale
            float ps = 0.0f;
            uint32_t pk[16];
#pragma unroll
            for (int nf = 0; nf < 8; ++nf) {
                float e0_ = exp2f(fmaf(sfr[nf][0], sc, -MB));
                float e1_ = exp2f(fmaf(sfr[nf][1], sc, -MB));
                float e2_ = exp2f(fmaf(sfr[nf][2], sc, -MB));
                float e3_ = exp2f(fmaf(sfr[nf][3], sc, -MB));
                ps += (e0_ + e1_) + (e2_ + e3_);
                pk[nf * 2 + 0] = cvtpk(e0_, e1_);
                pk[nf * 2 + 1] = cvtpk(e2_, e3_);
            }
            l_r += ps;   // lane-local; cross-lane reduce deferred to epilogue

            // In-register P transpose: 16 ds_permute pushes (block-replicated routing)
            uint32_t pw[4][4];
#pragma unroll
            for (int cc = 0; cc < 4; ++cc) {
                uint32_t r0 = (uint32_t)__builtin_amdgcn_ds_permute(idxA, (int)(s0 ? pk[cc * 4 + 2] : pk[cc * 4 + 0]));
                uint32_t r1 = (uint32_t)__builtin_amdgcn_ds_permute(idxA, (int)(s0 ? pk[cc * 4 + 3] : pk[cc * 4 + 1]));
                uint32_t r2 = (uint32_t)__builtin_amdgcn_ds_permute(idxB, (int)(s0 ? pk[cc * 4 + 0] : pk[cc * 4 + 2]));
                uint32_t r3 = (uint32_t)__builtin_amdgcn_ds_permute(idxB, (int)(s0 ? pk[cc * 4 + 1] : pk[cc * 4 + 3]));
                pw[cc][0] = hi ? r2 : r0;
                pw[cc][1] = hi ? r3 : r1;
                pw[cc][2] = hi ? r0 : r2;
                pw[cc][3] = hi ? r1 : r3;
            }

            // O^T += V^T P : A = V^T rows from LDS, B = P fragment (in-register)
            __builtin_amdgcn_s_setprio(1);
#pragma unroll
            for (int cc = 0; cc < 4; ++cc) {
                union { uint32_t u[4]; short8 s; } pb;
                pb.u[0] = pw[cc][0]; pb.u[1] = pw[cc][1];
                pb.u[2] = pw[cc][2]; pb.u[3] = pw[cc][3];
#pragma unroll
                for (int df = 0; df < 4; ++df) {
                    int row = df * 16 + lr;
                    short8 vb_ = *reinterpret_cast<const short8*>(
                        vb + row * 256 + (((cc * 4 + g) ^ ((row & 7) << 1)) << 4));
                    acc[df] = __builtin_amdgcn_mfma_f32_16x16x32_bf16(vb_, pb.s, acc[df], 0, 0, 0);
                }
            }
            __builtin_amdgcn_s_setprio(0);

            // all LDS reads from this buffer done before DMA overwrites it
            asm volatile("s_waitcnt lgkmcnt(0)" ::: "memory");
            __builtin_amdgcn_sched_barrier(0);
            __builtin_amdgcn_s_barrier();
            __builtin_amdgcn_sched_barrier(0);

            int nx = (kt + 2 < t1) ? kt + 2 : t1 - 1;   // clamped dummy keeps vmcnt uniform
            ASTAGE(nx, cur);
        }
    }
    asm volatile("s_waitcnt vmcnt(0)" ::: "memory");

    // epilogue: single cross-lane l reduce; store partial O^T (bf16) + l
    l_r += __shfl_xor(l_r, 16);
    l_r += __shfl_xor(l_r, 32);
    const int pidx = ((b * 256 + qblk * 8 + wid) * 4 + f);
    uint32_t* po = pO32 + (size_t)pidx * 512;
#pragma unroll
    for (int df = 0; df < 4; ++df) {
        po[(df * 8 + 2 * g + 0) * 16 + lr] = cvtpk(acc[df][0], acc[df][1]);
        po[(df * 8 + 2 * g + 1) * 16 + lr] = cvtpk(acc[df][2], acc[df][3]);
    }
    if (g == 0) pml[(size_t)pidx * 16 + lr] = l_r;
}

// ---------- Combine partials (weight-free: static softmax bias) ----------
__global__ __launch_bounds__(64) void combine_kernel(
    const uint32_t* __restrict__ pO32, const float* __restrict__ pml,
    float* __restrict__ out)
{
    const int t = threadIdx.x;
    const int q = t & 15, dblk = t >> 4;
    const int grp = blockIdx.x;          // b*256 + qt16
    const int b = grp >> 8, qt = grp & 255;
    const int qb = qt * 16;

    float l = 0.0f;
#pragma unroll
    for (int f = 0; f < 4; ++f) l += pml[(size_t)(grp * 4 + f) * 16 + q];

    float o[16];
#pragma unroll
    for (int i = 0; i < 16; ++i) o[i] = 0.0f;
#pragma unroll
    for (int f = 0; f < 4; ++f) {
        const uint32_t* src = pO32 + (size_t)(grp * 4 + f) * 512 + dblk * 128 + q;
#pragma unroll
        for (int r0 = 0; r0 < 8; ++r0) {
            uint32_t u = src[r0 * 16];
            o[2 * r0 + 0] += bf2f_lo(u);
            o[2 * r0 + 1] += bf2f_hi(u);
        }
    }
    float inv = 1.0f / l;
    float* op = out + ((size_t)b * SS + qb + q) * DD + dblk * 16;
#pragma unroll
    for (int i = 0; i < 4; ++i) {
        float4 st;
        st.x = o[4 * i + 0] * inv; st.y = o[4 * i + 1] * inv;
        st.z = o[4 * i + 2] * inv; st.w = o[4 * i + 3] * inv;
        *reinterpret_cast<float4*>(op + 4 * i) = st;
    }
}

extern "C" void kernel_launch(void* const* d_in, const int* in_sizes, int n_in,
                              void* d_out, int out_size, void* d_ws, size_t ws_size,
                              hipStream_t stream) {
    const float* x  = (const float*)d_in[0];
    const float* Wk = (const float*)d_in[1];
    const float* Wq = (const float*)d_in[2];
    const float* Wv = (const float*)d_in[3];
    ushort* q_ws  = (ushort*)d_ws;
    ushort* k_ws  = q_ws + (size_t)BB * SS * DD;
    ushort* vT_ws = k_ws + (size_t)BB * SS * DD;
    ushort* Wb    = vT_ws + (size_t)BB * SS * DD;
    uint32_t* pO32 = (uint32_t*)(Wb + 192 * 1024);          // 4096 * 512 u32 = 8 MB
    float* pml     = (float*)(pO32 + (size_t)4096 * 512);   // 4096 * 16 f32 = 256 KB
    float* out = (float*)d_out;

    hipLaunchKernelGGL(wconv_kernel, dim3(96), dim3(256), 0, stream, Wq, Wk, Wv, Wb);
    hipLaunchKernelGGL(proj_kernel, dim3(BB * SS / 64), dim3(256), 0, stream,
                       x, Wb, q_ws, k_ws, vT_ws);
    hipLaunchKernelGGL(attn_kernel, dim3(BB * 32 * 4), dim3(512), 0, stream,
                       q_ws, k_ws, vT_ws, pO32, pml);
    hipLaunchKernelGGL(combine_kernel, dim3(BB * SS / 16), dim3(64), 0, stream,
                       pO32, pml, out);
}